// Round 13
// baseline (110.320 us; speedup 1.0000x reference)
//
#include <hip/hip_runtime.h>
#include <cmath>

#define B_N 65536
#define C_N 128
#define D_N 32
#define K_N 10
#define EPS_F 1e-12f
#define SCALE_F (-0.72134752044448169f)   // -0.5 * log2(e)

#define NKK 48                    // 45 live K-steps + 3 zero pads
#define CHUNK_F16 4096            // per-step Q chunk: 4ct x 2hl x 64lane x 8 f16 = 8 KB
#define QF_N (NKK * CHUNK_F16)
#define YSTR 33                   // shared-y row stride: bank=(row+e)%32, conflict-free

typedef _Float16 f16x8 __attribute__((ext_vector_type(8)));
typedef float    f32x16 __attribute__((ext_vector_type(16)));

// Step metadata (prep only), affine in (window w, row-pair r) order.
__device__ __forceinline__ void mdkk(int kk, int& dA, int& e0) {
    if (kk >= 45) { dA = 0; e0 = 0; return; }
    int w = (kk >= 17) + (kk >= 30) + (kk >= 39) + (kk >= 44);
    int off = w == 0 ? 0 : (w == 1 ? 17 : (w == 2 ? 30 : (w == 3 ? 39 : 44)));
    int r = kk - off;
    dA = 2 * r;
    e0 = 2 * r + 8 * w;
}

// ---------------------------------------------------------------------------
// Fused prep (unchanged): block = cluster c; packs Q chunks (zeros for pads):
//   QF[kk*4096 + ct*1024 + hl*512 + (half*32 + (c&31))*8 + j]
// ---------------------------------------------------------------------------
__global__ __launch_bounds__(128) void k_prep(const float* __restrict__ S,
                                              const float* __restrict__ mu,
                                              const int* __restrict__ onehot,
                                              _Float16* __restrict__ QF,
                                              int* __restrict__ cls) {
    const int c = blockIdx.x;
    const int tid = threadIdx.x;
    __shared__ float sSm[D_N];
    __shared__ float st3;

    if (tid < D_N) {
        const float* Sr = S + (size_t)c * (D_N * D_N) + (size_t)tid * D_N;
        const float* mr = mu + (size_t)c * D_N;
        float a0 = 0.f, a1 = 0.f;
#pragma unroll
        for (int e = 0; e < D_N; e += 2) {
            a0 = fmaf(Sr[e + 0], mr[e + 0], a0);
            a1 = fmaf(Sr[e + 1], mr[e + 1], a1);
        }
        sSm[tid] = a0 + a1;
    }
    __syncthreads();
    if (tid == 0) {
        const float* mr = mu + (size_t)c * D_N;
        float a = 0.f;
#pragma unroll
        for (int d = 0; d < D_N; ++d) a = fmaf(mr[d], sSm[d], a);
        st3 = a;
        int cl = 0;
#pragma unroll
        for (int k = 0; k < K_N; ++k)
            if (onehot[c * K_N + k] != 0) cl = k;
        cls[c] = cl;
    }
    __syncthreads();

    if (tid < 2 * NKK) {
        const int kk   = tid >> 1;
        const int half = tid & 1;
        int dA, e0;
        mdkk(kk, dA, e0);
        const int d  = dA + half;
        const int ct = c >> 5;
        const size_t base = (size_t)kk * CHUNK_F16 + ct * 1024
                          + (size_t)(half * 32 + (c & 31)) * 8;
        const float* Sc = S + (size_t)c * (D_N * D_N);
        for (int j = 0; j < 8; ++j) {
            const int e = e0 + j;
            float q = 0.f;
            if (kk < 45 && d <= e && e <= 32) {
                float v;
                if (e < 32)      v = Sc[d * D_N + e] * (d == e ? 1.f : 2.f);
                else if (d < 32) v = -2.f * sSm[d];
                else             v = st3;          // d == e == 32
                q = SCALE_F * v;
            }
            _Float16 h = (_Float16)q;
            QF[base + j]       = h;                         // hi
            QF[base + 512 + j] = (_Float16)(q - (float)h);  // lo
        }
    }
}

// ---------------------------------------------------------------------------
__device__ __forceinline__ void gl_lds16(const void* g, void* l) {
    __builtin_amdgcn_global_load_lds(
        (const __attribute__((address_space(1))) unsigned int*)g,
        (__attribute__((address_space(3))) unsigned int*)l, 16, 0, 0);
}

// phi build via packed RTZ converts; f16x8 assembled by word copies.
__device__ __forceinline__ void mkphi(float yd, const float (&yw)[8],
                                      f16x8& ph, f16x8& pl) {
    union { unsigned int w[4]; f16x8 v; } H, L;
#pragma unroll
    for (int p = 0; p < 4; ++p) {
        float f0 = yd * yw[2 * p], f1 = yd * yw[2 * p + 1];
        auto h2 = __builtin_amdgcn_cvt_pkrtz(f0, f1);
        float r0 = f0 - (float)h2[0];
        float r1 = f1 - (float)h2[1];
        auto l2 = __builtin_amdgcn_cvt_pkrtz(r0, r1);
        __builtin_memcpy(&H.w[p], &h2, 4);
        __builtin_memcpy(&L.w[p], &l2, 4);
    }
    ph = H.v;
    pl = L.v;
}

// ---------------------------------------------------------------------------
// Main v10: 4 waves/SIMD (the knob never turned: v6/v7/v9 all ~50us at
// 2 waves/SIMD with both pipes <46% busy -> stall-bound, not pipe-bound).
// Block = 512 threads, 8 waves = 4 row-groups x 2 c-halves, 128 rows x 128 c;
// grid 512 -> 2 blocks/CU = 16 waves/CU. Register budget for 4 waves/SIMD
// (<=128 total): acc = 2 tiles = 32 AGPR, direct-consume Q, launch_bounds
// (512,4). Shared y (one copy/row, bank-free) + sliding window (e0 +2/step
// within family -> 3 b32/step instead of 9). Ring-4 chunk buffer, stage
// distance 2, counted per-wave vmcnt (1 gl_lds/wave/step).
// ---------------------------------------------------------------------------
__global__ __launch_bounds__(512, 4) void k_mainv10(const float* __restrict__ data,
                                                    const _Float16* __restrict__ QF,
                                                    const int* __restrict__ clsp,
                                                    float* __restrict__ out) {
    const int tid  = threadIdx.x;
    const int lane = tid & 63;
    const int wid  = tid >> 6;      // 0..7
    const int rg   = wid >> 1;      // row-group: rows rg*32..rg*32+31
    const int cg   = wid & 1;       // c-half: tiles {2cg, 2cg+1}
    const int col  = lane & 31;
    const bool hi  = lane >= 32;
    const int bb   = blockIdx.x * 128;

    __shared__ float sy[128 * YSTR + 64];
    __shared__ alignas(16) _Float16 qb[4 * CHUNK_F16];
    __shared__ int lcls[C_N];
    __shared__ float scr[4][2][32][14];   // combine scratch [rg][cg][row][13]

    if (tid < C_N) lcls[tid] = clsp[tid];
    if (tid < 128) {                      // one y copy per row
        const float4* p0 = (const float4*)(data + (size_t)(bb + tid) * D_N);
        const int yb = tid * YSTR;
#pragma unroll
        for (int i = 0; i < 8; ++i) {
            float4 v = p0[i];
            sy[yb + 4 * i + 0] = v.x;
            sy[yb + 4 * i + 1] = v.y;
            sy[yb + 4 * i + 2] = v.z;
            sy[yb + 4 * i + 3] = v.w;
        }
        sy[yb + 32] = 1.f;                // homogeneous slot
    } else if (tid < 192) {
        sy[128 * YSTR + (tid - 128)] = 0.f;   // tail pad (row 127 overrun)
    }

    f32x16 acc[2];
#pragma unroll
    for (int lt = 0; lt < 2; ++lt)
#pragma unroll
        for (int g = 0; g < 16; ++g) acc[lt][g] = 0.f;

    // prologue: stage chunks 0,1 (1 KB slot per wave); full drain covers sy
    gl_lds16(QF + 0 * CHUNK_F16 + wid * 512 + lane * 8, qb + 0 * CHUNK_F16 + wid * 512);
    gl_lds16(QF + 1 * CHUNK_F16 + wid * 512 + lane * 8, qb + 1 * CHUNK_F16 + wid * 512);
    __syncthreads();

    const int hioff = hi ? 1 : 0;
    const float* yrow = sy + (rg * 32 + col) * YSTR;   // lane's row (shared copy)
    float yw[8], yd = 0.f;
    int e0 = 0, dAh = hioff;

#pragma clang loop unroll(disable)
    for (int t = 0; t < NKK; ++t) {
        // own stage from phase t-1 landed; barrier -> chunk t+1 complete block-wide
        asm volatile("s_waitcnt vmcnt(0)" ::: "memory");
        __builtin_amdgcn_s_barrier();
        __builtin_amdgcn_sched_barrier(0);
        if (t + 2 < NKK)
            gl_lds16(QF + (size_t)(t + 2) * CHUNK_F16 + wid * 512 + lane * 8,
                     qb + ((t + 2) & 3) * CHUNK_F16 + wid * 512);

        // y window for step t (family starts: full reload; else slide by 2)
        if (t == 0 || t == 17 || t == 30 || t == 39 || t == 44) {
            e0  = (t == 0) ? 0 : (t == 17) ? 8 : (t == 30) ? 16 : (t == 39) ? 24 : 32;
            dAh = hioff;                  // dA = 0 at each family start
#pragma unroll
            for (int j = 0; j < 8; ++j) yw[j] = yrow[e0 + j];
            yd = yrow[dAh];
        } else if (t < 45) {
            e0 += 2; dAh += 2;
            yw[0] = yw[2]; yw[1] = yw[3]; yw[2] = yw[4];
            yw[3] = yw[5]; yw[4] = yw[6]; yw[5] = yw[7];
            yw[6] = yrow[e0 + 6];
            yw[7] = yrow[e0 + 7];
            yd = yrow[dAh];
        }                                 // t >= 45: pads, Q=0, y irrelevant

        // Q fragments: this wave's 2 tiles from ring slot t&3
        const f16x8* qc = (const f16x8*)(qb + ((t & 3) * CHUNK_F16) + cg * 2048);
        f16x8 qh0 = qc[lane],       ql0 = qc[64 + lane];
        f16x8 qh1 = qc[128 + lane], ql1 = qc[192 + lane];

        f16x8 ph, pl;
        mkphi(yd, yw, ph, pl);
        __builtin_amdgcn_s_setprio(1);
        acc[0] = __builtin_amdgcn_mfma_f32_32x32x16_f16(qh0, ph, acc[0], 0, 0, 0);
        acc[1] = __builtin_amdgcn_mfma_f32_32x32x16_f16(qh1, ph, acc[1], 0, 0, 0);
        acc[0] = __builtin_amdgcn_mfma_f32_32x32x16_f16(ql0, ph, acc[0], 0, 0, 0);
        acc[1] = __builtin_amdgcn_mfma_f32_32x32x16_f16(ql1, ph, acc[1], 0, 0, 0);
        acc[0] = __builtin_amdgcn_mfma_f32_32x32x16_f16(qh0, pl, acc[0], 0, 0, 0);
        acc[1] = __builtin_amdgcn_mfma_f32_32x32x16_f16(qh1, pl, acc[1], 0, 0, 0);
        __builtin_amdgcn_s_setprio(0);
    }

    // ---------------- epilogue: per-wave partials over its 64 c --------------
    // C/D layout (HW-verified): col=lane&31 (b), c = gt*32+(g&3)+8*(g>>2)+4*hi
    const float hoff = hi ? 4.f : 0.f;
    const int* lc = lcls + (hi ? 4 : 0);
    float sum = 0.f, gmax = -1.f, gcf = 0.f;
    float a0 = 0, a1 = 0, a2 = 0, a3 = 0, a4 = 0, a5 = 0, a6 = 0, a7 = 0, a8 = 0, a9 = 0;
#pragma unroll
    for (int lt = 0; lt < 2; ++lt) {
        const int gt = cg * 2 + lt;       // global c-tile
        float psum = 0.f;
#pragma unroll
        for (int g = 0; g < 16; ++g) {
            float v = acc[lt][g];
            float gm;
            asm("v_exp_f32 %0, %1" : "=v"(gm) : "v"(v));   // 2^v = exp(-0.5 d2)
            const int cbase = gt * 32 + (g & 3) + 8 * (g >> 2);
            int cl = lc[cbase];
            psum += gm;
            float cf = (float)cbase + hoff;
            if (gm > gmax) { gmax = gm; gcf = cf; }        // c scanned ascending
            a0 += (cl == 0) ? gm : 0.f;
            a1 += (cl == 1) ? gm : 0.f;
            a2 += (cl == 2) ? gm : 0.f;
            a3 += (cl == 3) ? gm : 0.f;
            a4 += (cl == 4) ? gm : 0.f;
            a5 += (cl == 5) ? gm : 0.f;
            a6 += (cl == 6) ? gm : 0.f;
            a7 += (cl == 7) ? gm : 0.f;
            a8 += (cl == 8) ? gm : 0.f;
            a9 += (cl == 9) ? gm : 0.f;
        }
        sum += psum;
    }

    // lane-pair merge (same rows, complementary c within the half)
    sum += __shfl_xor(sum, 32, 64);
    {
        float om = __shfl_xor(gmax, 32, 64);
        float oc = __shfl_xor(gcf, 32, 64);
        bool take = (om > gmax) || (om == gmax && oc < gcf);
        if (take) { gmax = om; gcf = oc; }
    }
    a0 += __shfl_xor(a0, 32, 64);
    a1 += __shfl_xor(a1, 32, 64);
    a2 += __shfl_xor(a2, 32, 64);
    a3 += __shfl_xor(a3, 32, 64);
    a4 += __shfl_xor(a4, 32, 64);
    a5 += __shfl_xor(a5, 32, 64);
    a6 += __shfl_xor(a6, 32, 64);
    a7 += __shfl_xor(a7, 32, 64);
    a8 += __shfl_xor(a8, 32, 64);
    a9 += __shfl_xor(a9, 32, 64);

    if (!hi) {                            // lanes 0-31 hold per-row partials
        float* s = scr[rg][cg][col];
        s[0] = sum; s[1] = gmax; s[2] = gcf;
        s[3] = a0; s[4] = a1; s[5] = a2; s[6] = a3; s[7] = a4;
        s[8] = a5; s[9] = a6; s[10] = a7; s[11] = a8; s[12] = a9;
    }
    __syncthreads();

    // cg==0 waves combine both c-halves and write final outputs
    if (cg == 0 && !hi) {
        const float* s0 = scr[rg][0][col];
        const float* s1 = scr[rg][1][col];
        float fs = s0[0] + s1[0];
        float gm = s0[1];
        float gc = s0[2];
        if (s1[1] > gm) { gm = s1[1]; gc = s1[2]; }   // tie -> lower c (cg0)
        float inv = 1.0f / (fs + EPS_F);
        float ls[K_N];
        float best = -1.f;
        int bk = 0;
#pragma unroll
        for (int k = 0; k < K_N; ++k) {
            ls[k] = (s0[3 + k] + s1[3 + k]) * inv;
            if (ls[k] > best) { best = ls[k]; bk = k; }
        }
        const int b = bb + rg * 32 + col;
        float2* o2 = (float2*)(out + (size_t)b * K_N);   // 40 B rows, 8 B aligned
#pragma unroll
        for (int k2 = 0; k2 < K_N / 2; ++k2)
            o2[k2] = make_float2(ls[2 * k2], ls[2 * k2 + 1]);
        out[(size_t)B_N * K_N + b] = (float)bk;
        out[(size_t)B_N * K_N + B_N + b] = gc;
    }
}

// ---------------------------------------------------------------------------
extern "C" void kernel_launch(void* const* d_in, const int* in_sizes, int n_in,
                              void* d_out, int out_size, void* d_ws, size_t ws_size,
                              hipStream_t stream) {
    const float* data   = (const float*)d_in[0];   // [B, D]
    const float* mu     = (const float*)d_in[1];   // [C, D]
    const float* S      = (const float*)d_in[2];   // [C, D, D]
    const int*   onehot = (const int*)d_in[3];     // [C, K]
    float* out = (float*)d_out;

    // ws: QF [QF_N f16] | cls [C]
    _Float16* QF  = (_Float16*)d_ws;
    int*      cls = (int*)(QF + QF_N);

    hipLaunchKernelGGL(k_prep, dim3(C_N), dim3(128), 0, stream,
                       S, mu, onehot, QF, cls);
    hipLaunchKernelGGL(k_mainv10, dim3(B_N / 128), dim3(512), 0, stream,
                       data, QF, cls, out);
}